// Round 7
// baseline (198.696 us; speedup 1.0000x reference)
//
#include <hip/hip_runtime.h>

#define HID 20
#define NLAY 7
#define NC 11
#define HHID 10
// comp indices: 0=val 1=gx 2=gy 3=gt 4=hxx 5=hxy 6=hyy 7=hxt 8=hyt 9=Lx 10=Ly

// Pin a value into an AGPR (write) / pull it back (read).
#define AGPR_WRITE(dst, src) asm("v_accvgpr_write_b32 %0, %1" : "=a"(dst) : "v"(src))
#define AGPR_READ(dst, src)  asm("v_accvgpr_read_b32 %0, %1" : "=v"(dst) : "a"(src))

// tanh and its first three derivatives, via one hardware exp.
__device__ __forceinline__ float tanh_derivs(float a, float& d1, float& d2, float& d3) {
    const float e = __expf(2.0f * a);
    const float s = 1.0f - __fdividef(2.0f, e + 1.0f);
    d1 = 1.0f - s * s;               // f'
    d2 = -2.0f * s * d1;             // f''
    d3 = -2.0f * (d1 * d1 + s * d2); // f'''
    return s;
}

__global__ void __launch_bounds__(256, 1)
pinn_kernel(const float* __restrict__ xs, const float* __restrict__ ys, const float* __restrict__ ts,
            const float* __restrict__ W_in, const float* __restrict__ b_in,
            const float* __restrict__ W_hid, const float* __restrict__ b_hid,
            const float* __restrict__ W_out, const float* __restrict__ b_out,
            const float* __restrict__ lam1p, const float* __restrict__ lam2p,
            float* __restrict__ out, int N)
{
    const int idx = blockIdx.x * blockDim.x + threadIdx.x;
    if (idx >= N) return;
    const float xv = xs[idx], yv = ys[idx], tv = ts[idx];
    const float l1 = lam1p[0], l2 = lam2p[0];

    float hA[HID][NC];   // jet state X (AGPR-pinned)
    float yA[HHID][NC];  // first-half stash Y (AGPR-pinned)

    // ---- input layer ----
    #pragma unroll
    for (int j = 0; j < HID; ++j) {
        const float w0 = W_in[j], w1 = W_in[HID + j], w2 = W_in[2 * HID + j];
        const float a0 = fmaf(xv, w0, fmaf(yv, w1, fmaf(tv, w2, b_in[j])));
        float d1, d2, d3;
        const float s = tanh_derivs(a0, d1, d2, d3);
        const float g2w = w0 * w0 + w1 * w1;
        float nv[NC];
        nv[0] = s;
        nv[1] = d1 * w0;
        nv[2] = d1 * w1;
        nv[3] = d1 * w2;
        nv[4] = d2 * w0 * w0;
        nv[5] = d2 * w0 * w1;
        nv[6] = d2 * w1 * w1;
        nv[7] = d2 * w0 * w2;
        nv[8] = d2 * w1 * w2;
        nv[9] = d3 * w0 * g2w;
        nv[10] = d3 * w1 * g2w;
        #pragma unroll
        for (int c = 0; c < NC; ++c) AGPR_WRITE(hA[j][c], nv[c]);
    }

    // ---- hidden layers: i-outer, half-width acc (110 VGPR hot) ----
    #pragma unroll 1
    for (int l = 0; l < NLAY; ++l) {
        const float* __restrict__ Wl = W_hid + l * HID * HID;
        const float* __restrict__ bl = b_hid + l * HID;

        #pragma unroll
        for (int hf = 0; hf < 2; ++hf) {
            float acc[HHID][NC];
            #pragma unroll
            for (int j = 0; j < HHID; ++j) {
                acc[j][0] = bl[hf * HHID + j];
                #pragma unroll
                for (int c = 1; c < NC; ++c) acc[j][c] = 0.0f;
            }
            #pragma unroll
            for (int i = 0; i < HID; ++i) {
                float r[NC];
                #pragma unroll
                for (int c = 0; c < NC; ++c) AGPR_READ(r[c], hA[i][c]);
                #pragma unroll
                for (int j = 0; j < HHID; ++j) {
                    const float w = Wl[i * HID + hf * HHID + j];
                    #pragma unroll
                    for (int c = 0; c < NC; ++c) acc[j][c] = fmaf(w, r[c], acc[j][c]);
                }
            }
            #pragma unroll
            for (int j = 0; j < HHID; ++j) {
                float d1, d2, d3;
                const float s = tanh_derivs(acc[j][0], d1, d2, d3);
                const float agx = acc[j][1], agy = acc[j][2], agt = acc[j][3];
                const float ahxx = acc[j][4], ahxy = acc[j][5], ahyy = acc[j][6];
                const float ahxt = acc[j][7], ahyt = acc[j][8];
                const float aLx = acc[j][9], aLy = acc[j][10];
                const float g2 = agx * agx + agy * agy;
                float nv[NC];
                nv[0] = s;
                nv[1] = d1 * agx;
                nv[2] = d1 * agy;
                nv[3] = d1 * agt;
                nv[4] = fmaf(d2, agx * agx, d1 * ahxx);
                nv[5] = fmaf(d2, agx * agy, d1 * ahxy);
                nv[6] = fmaf(d2, agy * agy, d1 * ahyy);
                nv[7] = fmaf(d2, agx * agt, d1 * ahxt);
                nv[8] = fmaf(d2, agy * agt, d1 * ahyt);
                nv[9]  = d3 * agx * g2 + d2 * (3.0f * agx * ahxx + 2.0f * agy * ahxy + agx * ahyy) + d1 * aLx;
                nv[10] = d3 * agy * g2 + d2 * (3.0f * agy * ahyy + 2.0f * agx * ahxy + agy * ahxx) + d1 * aLy;
                if (hf == 0) {
                    #pragma unroll
                    for (int c = 0; c < NC; ++c) AGPR_WRITE(yA[j][c], nv[c]);
                } else {
                    #pragma unroll
                    for (int c = 0; c < NC; ++c) AGPR_WRITE(hA[HHID + j][c], nv[c]);
                }
            }
        }
        // commit stash: X[0..9] = Y
        #pragma unroll
        for (int j = 0; j < HHID; ++j) {
            #pragma unroll
            for (int c = 0; c < NC; ++c) {
                float t;
                AGPR_READ(t, yA[j][c]);
                AGPR_WRITE(hA[j][c], t);
            }
        }
    }

    // ---- output layer: psi = col 0, p = col 1 ----
    float su = 0, sv = 0, sp = 0, sux = 0, suy = 0, svx = 0;
    float spx = 0, spy = 0, sut = 0, svt = 0, slx = 0, sly = 0;
    #pragma unroll
    for (int i = 0; i < HID; ++i) {
        const float w0 = W_out[2 * i], w1 = W_out[2 * i + 1];
        float r[NC];
        #pragma unroll
        for (int c = 0; c < NC; ++c) AGPR_READ(r[c], hA[i][c]);
        sp  = fmaf(w1, r[0], sp);
        sv  = fmaf(w0, r[1], sv);   // psi_x
        su  = fmaf(w0, r[2], su);   // psi_y
        spx = fmaf(w1, r[1], spx);
        spy = fmaf(w1, r[2], spy);
        svx = fmaf(w0, r[4], svx);  // psi_xx
        sux = fmaf(w0, r[5], sux);  // psi_xy
        suy = fmaf(w0, r[6], suy);  // psi_yy
        svt = fmaf(w0, r[7], svt);  // psi_xt
        sut = fmaf(w0, r[8], sut);  // psi_yt
        slx = fmaf(w0, r[9], slx);
        sly = fmaf(w0, r[10], sly);
    }

    const float u = su;
    const float v = -sv;
    const float p = sp + b_out[1];
    const float ux = sux, uy = suy;
    const float vx = -svx, vy = -sux;
    const float px = spx, py = spy;
    const float ut = sut, vt = -svt;
    const float lx = slx, ly = sly;

    const float fu = ut + l1 * (u * ux + v * uy) + px - l2 * ly;
    const float fv = vt + l1 * (u * vx + v * vy) + py + l2 * lx;

    out[idx]         = u;
    out[N + idx]     = v;
    out[2 * N + idx] = p;
    out[3 * N + idx] = fu;
    out[4 * N + idx] = fv;
}

extern "C" void kernel_launch(void* const* d_in, const int* in_sizes, int n_in,
                              void* d_out, int out_size, void* d_ws, size_t ws_size,
                              hipStream_t stream) {
    const float* xs    = (const float*)d_in[0];
    const float* ys    = (const float*)d_in[1];
    const float* ts    = (const float*)d_in[2];
    const float* W_in  = (const float*)d_in[3];
    const float* b_in  = (const float*)d_in[4];
    const float* W_hid = (const float*)d_in[5];
    const float* b_hid = (const float*)d_in[6];
    const float* W_out = (const float*)d_in[7];
    const float* b_out = (const float*)d_in[8];
    const float* lam1  = (const float*)d_in[9];
    const float* lam2  = (const float*)d_in[10];
    float* out = (float*)d_out;

    const int N = in_sizes[0];
    const int block = 256;
    const int grid = (N + block - 1) / block;
    pinn_kernel<<<grid, block, 0, stream>>>(xs, ys, ts, W_in, b_in, W_hid, b_hid,
                                            W_out, b_out, lam1, lam2, out, N);
}